// Round 1
// baseline (718.537 us; speedup 1.0000x reference)
//
#include <hip/hip_runtime.h>

// TeamMovementModel: 1472 LSTM sequences (1408 player + 64 ball), T=128, H=128, D=2,
// then FC (40 x 256) on [player_h ; ball_h].
//
// Kernel 1 (lstm_kernel): one block per sequence, 512 threads = one gate row per
// thread, W_hh row register-resident (128 VGPRs). h in LDS, broadcast reads.
// Kernel 2 (fc_kernel): one block per (b,p), 64 threads, staged combine in LDS.

#define HDIM 128
#define TSTEPS 128
#define NPLAYER 1408   // 64*22
#define NSEQ 1472      // + 64 ball

__device__ __forceinline__ float rcp_fast(float x) { return __builtin_amdgcn_rcpf(x); }
__device__ __forceinline__ float sigmoid_f(float x) {
    return rcp_fast(1.0f + __expf(-x));
}
__device__ __forceinline__ float tanh_f(float x) {
    // tanh(x) = 1 - 2/(e^{2x}+1); stable at both extremes (rcp(inf)=0)
    return 1.0f - 2.0f * rcp_fast(__expf(2.0f * x) + 1.0f);
}

__global__ void __launch_bounds__(512, 2)
lstm_kernel(const float* __restrict__ x_players, const float* __restrict__ x_ball,
            const float* __restrict__ p_w_ih, const float* __restrict__ p_w_hh,
            const float* __restrict__ p_b_ih, const float* __restrict__ p_b_hh,
            const float* __restrict__ b_w_ih, const float* __restrict__ b_w_hh,
            const float* __restrict__ b_b_ih, const float* __restrict__ b_b_hh,
            float* __restrict__ h_all)
{
    const int seq = blockIdx.x;      // 0..1471
    const int t   = threadIdx.x;     // 0..511 : gate row (i[0:128) f[128:256) g[256:384) o[384:512))
    const bool ball = (seq >= NPLAYER);

    const float* w_ih = ball ? b_w_ih : p_w_ih;
    const float* w_hh = ball ? b_w_hh : p_w_hh;
    const float* bih  = ball ? b_b_ih : p_b_ih;
    const float* bhh  = ball ? b_b_hh : p_b_hh;
    const float* x    = ball ? (x_ball    + (size_t)(seq - NPLAYER) * TSTEPS * 2)
                             : (x_players + (size_t)seq * TSTEPS * 2);

    __shared__ __align__(16) float h_sh[HDIM];
    __shared__ __align__(16) float x_sh[TSTEPS * 2];
    __shared__ float gates_sh[4 * HDIM];

    // stage the sequence input (256 floats) and init h
    if (t < TSTEPS * 2) x_sh[t] = x[t];
    if (t < HDIM) h_sh[t] = 0.0f;

    // W_hh row for this gate -> registers (128 VGPRs)
    float w[HDIM];
    {
        const float* wrow = w_hh + (size_t)t * HDIM;
        #pragma unroll
        for (int k = 0; k < HDIM; k += 4) {
            float4 v = *(const float4*)(wrow + k);
            w[k] = v.x; w[k + 1] = v.y; w[k + 2] = v.z; w[k + 3] = v.w;
        }
    }
    const float wi0  = w_ih[t * 2 + 0];
    const float wi1  = w_ih[t * 2 + 1];
    const float bias = bih[t] + bhh[t];
    float c = 0.0f;   // cell state, owned by threads 0..127

    __syncthreads();

    for (int step = 0; step < TSTEPS; ++step) {
        const float x0 = x_sh[2 * step];
        const float x1 = x_sh[2 * step + 1];
        float a0 = __builtin_fmaf(wi1, x1, __builtin_fmaf(wi0, x0, bias));
        float a1 = 0.0f, a2 = 0.0f, a3 = 0.0f;
        #pragma unroll
        for (int k = 0; k < HDIM; k += 4) {
            float4 hv = *(const float4*)(h_sh + k);   // wave-uniform broadcast read
            a0 = __builtin_fmaf(w[k],     hv.x, a0);
            a1 = __builtin_fmaf(w[k + 1], hv.y, a1);
            a2 = __builtin_fmaf(w[k + 2], hv.z, a2);
            a3 = __builtin_fmaf(w[k + 3], hv.w, a3);
        }
        const float g = (a0 + a1) + (a2 + a3);
        // g-gate rows get tanh, the rest sigmoid (wave-uniform branch: 128-wide ranges)
        const float act = (t >= 2 * HDIM && t < 3 * HDIM) ? tanh_f(g) : sigmoid_f(g);
        gates_sh[t] = act;
        __syncthreads();
        if (t < HDIM) {
            const float ig = gates_sh[t];
            const float fg = gates_sh[t + HDIM];
            const float gg = gates_sh[t + 2 * HDIM];
            const float og = gates_sh[t + 3 * HDIM];
            c = __builtin_fmaf(fg, c, ig * gg);
            h_sh[t] = og * tanh_f(c);
        }
        __syncthreads();
    }

    if (t < HDIM) h_all[(size_t)seq * HDIM + t] = h_sh[t];
}

__global__ void __launch_bounds__(64)
fc_kernel(const float* __restrict__ h_all, const float* __restrict__ fc_w,
          const float* __restrict__ fc_b, float* __restrict__ out)
{
    const int blk = blockIdx.x;        // 0..1407 == b*22 + p
    const int b   = blk / 22;
    const int t   = threadIdx.x;       // 0..63

    __shared__ __align__(16) float comb[2 * HDIM];
    for (int i = t; i < HDIM; i += 64) {
        comb[i]        = h_all[(size_t)blk * HDIM + i];
        comb[HDIM + i] = h_all[(size_t)(NPLAYER + b) * HDIM + i];
    }
    __syncthreads();

    if (t < 40) {
        const float* wr = fc_w + (size_t)t * 2 * HDIM;
        float acc = fc_b[t];
        float a1 = 0.0f, a2 = 0.0f, a3 = 0.0f;
        #pragma unroll
        for (int k = 0; k < 2 * HDIM; k += 4) {
            float4 wv = *(const float4*)(wr + k);
            float4 cv = *(const float4*)(comb + k);
            acc = __builtin_fmaf(wv.x, cv.x, acc);
            a1  = __builtin_fmaf(wv.y, cv.y, a1);
            a2  = __builtin_fmaf(wv.z, cv.z, a2);
            a3  = __builtin_fmaf(wv.w, cv.w, a3);
        }
        out[(size_t)blk * 40 + t] = acc + (a1 + a2) + a3;
    }
}

extern "C" void kernel_launch(void* const* d_in, const int* in_sizes, int n_in,
                              void* d_out, int out_size, void* d_ws, size_t ws_size,
                              hipStream_t stream) {
    const float* x_players = (const float*)d_in[0];
    const float* x_ball    = (const float*)d_in[1];
    const float* p_w_ih    = (const float*)d_in[2];
    const float* p_w_hh    = (const float*)d_in[3];
    const float* p_b_ih    = (const float*)d_in[4];
    const float* p_b_hh    = (const float*)d_in[5];
    const float* b_w_ih    = (const float*)d_in[6];
    const float* b_w_hh    = (const float*)d_in[7];
    const float* b_b_ih    = (const float*)d_in[8];
    const float* b_b_hh    = (const float*)d_in[9];
    const float* fc_w      = (const float*)d_in[10];
    const float* fc_b      = (const float*)d_in[11];

    float* h_all = (float*)d_ws;   // NSEQ * HDIM floats = 753,664 B

    lstm_kernel<<<dim3(NSEQ), dim3(512), 0, stream>>>(
        x_players, x_ball, p_w_ih, p_w_hh, p_b_ih, p_b_hh,
        b_w_ih, b_w_hh, b_b_ih, b_b_hh, h_all);

    fc_kernel<<<dim3(NPLAYER), dim3(64), 0, stream>>>(
        h_all, fc_w, fc_b, (float*)d_out);
}